// Round 16
// baseline (195.871 us; speedup 1.0000x reference)
//
#include <hip/hip_runtime.h>

namespace {
constexpr int kB = 2;
constexpr int kH = 352;
constexpr int kW = 1216;
constexpr int kHW = kH * kW;        // 428032
constexpr int kN = kB * kHW;        // 856064
constexpr float kDmax = 80.0f;
constexpr float kEps = 1e-6f;
constexpr int kBlock = 256;         // step kernels
constexpr int kBlockP = 128;        // prep blocks
constexpr int kStepGrid = 512;      // exactly 2 blocks/CU
constexpr int kUnitsPerBlk = 209;   // 512*209 = kN/8 exactly -> perfect balance
}

typedef _Float16 half_t;
typedef __attribute__((ext_vector_type(4))) _Float16 half4;
typedef __attribute__((ext_vector_type(8))) _Float16 half8;

// Module-owned workspace, fully rewritten from inputs on every launch.
__device__ half_t g_Wh[(size_t)48 * kN];  // merged weights, fp16, ch-major (~82 MB)
__device__ float  g_Q[kN];                // fp32 constant term
__device__ float  g_ping[kN];             // Dt ping buffer

__device__ __forceinline__ float4 ld4(const float* p) { return *(const float4*)p; }
__device__ __forceinline__ float4 f4add(float4 a, float4 b) {
    return make_float4(a.x + b.x, a.y + b.y, a.z + b.z, a.w + b.w);
}
__device__ __forceinline__ float4 f4mul(float4 a, float4 b) {
    return make_float4(a.x * b.x, a.y * b.y, a.z * b.z, a.w * b.w);
}
__device__ __forceinline__ float4 f4fma(float4 a, float4 b, float4 c) {
    return make_float4(fmaf(a.x, b.x, c.x), fmaf(a.y, b.y, c.y),
                       fmaf(a.z, b.z, c.z), fmaf(a.w, b.w, c.w));
}
__device__ __forceinline__ float4 f4abs(float4 a) {
    return make_float4(fabsf(a.x), fabsf(a.y), fabsf(a.z), fabsf(a.w));
}
__device__ __forceinline__ float4 f4max(float4 a, float4 b) {
    return make_float4(fmaxf(a.x, b.x), fmaxf(a.y, b.y),
                       fmaxf(a.z, b.z), fmaxf(a.w, b.w));
}
__device__ __forceinline__ half4 toh4(float4 v) {
    half4 h;
    h[0] = (half_t)v.x; h[1] = (half_t)v.y; h[2] = (half_t)v.z; h[3] = (half_t)v.w;
    return h;
}
__device__ __forceinline__ float4 tof4(half4 h) {
    return make_float4((float)h[0], (float)h[1], (float)h[2], (float)h[3]);
}

// Single-pass merged-weight precompute + fused first step.
// R15 change: DROP the a5 stash. a5 is streamed only for its abs-sum; the
// merge re-loads its 24 taps from GLOBAL (the 51 KB/block region was just
// read -> L2/L3 hits; also full-fp32 a5 in merge now). LDS 74 -> 49 KB =>
// 3 blocks/CU = 6 waves/CU (was 4). This is the first VALID concurrency A/B:
// R14's block-size change kept waves/CU constant at 4 (2 waves x 2 blocks).
// If prep stays ~138 us at 6 waves with identical load width, the ~2.8 TB/s
// demand-rate read wall is confirmed at two occupancies -> roofline.
__global__ __launch_bounds__(kBlockP) void prep_kernel(
    const float* __restrict__ D0, const float* __restrict__ DL,
    const float* __restrict__ ML, const float* __restrict__ A3,
    const float* __restrict__ A5, const float* __restrict__ A7,
    const float* __restrict__ SG, const float* __restrict__ AL)
{
    __shared__ half_t sh7[49 * kBlockP * 4];   // 50176 B -> 3 blocks/CU

    int tid = threadIdx.x;
    int t = blockIdx.x * kBlockP + tid;       // 0 .. kN/4-1
    int p = t * 4;
    int b = p / kHW;                          // kHW % 512 == 0: block batch-uniform
    int rem = p - b * kHW;
    int y = rem / kW;                         // kW % 4 == 0: 4-px group stays in row
    int x0 = rem - y * kW;
    int sb = tid * 4;                         // this thread's LDS pixel base

    const float* a3p = A3 + (size_t)b * 9 * kHW + rem;
    const float* a5p = A5 + (size_t)b * 25 * kHW + rem;
    const float* a7p = A7 + (size_t)b * 49 * kHW + rem;
    const float* sgp = SG + (size_t)b * 3 * kHW + rem;
    const float* d0b = D0 + (size_t)b * kHW;

    float4 zero = make_float4(0.f, 0.f, 0.f, 0.f);

    // ---- Stream a7: 6x8 batches + 1; abs-sum, stash fp16 ----
    float4 s7v = zero, c7v = zero;
#pragma unroll
    for (int ch = 0; ch < 6; ++ch) {
        float4 buf[8];
#pragma unroll
        for (int j = 0; j < 8; ++j) buf[j] = ld4(a7p + (size_t)(ch * 8 + j) * kHW);
#pragma unroll
        for (int j = 0; j < 8; ++j) {
            int c = ch * 8 + j;
            if (c == 24) c7v = buf[j];
            s7v = f4add(s7v, f4abs(buf[j]));
            *(half4*)(&sh7[c * (kBlockP * 4) + sb]) = toh4(buf[j]);
        }
    }
    {
        float4 l = ld4(a7p + (size_t)48 * kHW);
        s7v = f4add(s7v, f4abs(l));
        *(half4*)(&sh7[48 * (kBlockP * 4) + sb]) = toh4(l);
    }

    // ---- Stream a5: abs-sum ONLY (no stash; merge re-reads from L2/L3) ----
    float4 s5v = zero, c5v = zero;
#pragma unroll
    for (int ch = 0; ch < 3; ++ch) {
        float4 buf[8];
#pragma unroll
        for (int j = 0; j < 8; ++j) buf[j] = ld4(a5p + (size_t)(ch * 8 + j) * kHW);
#pragma unroll
        for (int j = 0; j < 8; ++j) {
            int c = ch * 8 + j;
            if (c == 12) c5v = buf[j];
            s5v = f4add(s5v, f4abs(buf[j]));
        }
    }
    s5v = f4add(s5v, f4abs(ld4(a5p + (size_t)24 * kHW)));

    // ---- a3 stays in registers (9 float4 = 36 VGPR) ----
    float4 a3r[9];
    float4 s3v = zero;
#pragma unroll
    for (int c = 0; c < 9; ++c) a3r[c] = ld4(a3p + (size_t)c * kHW);
#pragma unroll
    for (int c = 0; c < 9; ++c) s3v = f4add(s3v, f4abs(a3r[c]));

    // ---- Per-pixel scalars ----
    float4 g0 = ld4(sgp);
    float4 g1 = ld4(sgp + kHW);
    float4 g2 = ld4(sgp + 2 * kHW);
    float4 mx = f4max(g0, f4max(g1, g2));
    float4 e0 = make_float4(expf(g0.x - mx.x), expf(g0.y - mx.y), expf(g0.z - mx.z), expf(g0.w - mx.w));
    float4 e1 = make_float4(expf(g1.x - mx.x), expf(g1.y - mx.y), expf(g1.z - mx.z), expf(g1.w - mx.w));
    float4 e2 = make_float4(expf(g2.x - mx.x), expf(g2.y - mx.y), expf(g2.z - mx.z), expf(g2.w - mx.w));
    float4 einv = make_float4(1.f / (e0.x + e1.x + e2.x), 1.f / (e0.y + e1.y + e2.y),
                              1.f / (e0.z + e1.z + e2.z), 1.f / (e0.w + e1.w + e2.w));

    float4 alv = ld4(AL + p);
    float4 ml  = ld4(ML + p);
    float4 al = make_float4(fminf(fmaxf(alv.x, 0.f), 1.f), fminf(fmaxf(alv.y, 0.f), 1.f),
                            fminf(fmaxf(alv.z, 0.f), 1.f), fminf(fmaxf(alv.w, 0.f), 1.f));
    float4 mk = make_float4(ml.x > 0.5f ? 1.f : 0.f, ml.y > 0.5f ? 1.f : 0.f,
                            ml.z > 0.5f ? 1.f : 0.f, ml.w > 0.5f ? 1.f : 0.f);
    float4 g = f4mul(al, mk);
    float4 omg = make_float4(1.f - g.x, 1.f - g.y, 1.f - g.z, 1.f - g.w);

    float4 w3 = make_float4(omg.x * e0.x * einv.x / (s3v.x + kEps), omg.y * e0.y * einv.y / (s3v.y + kEps),
                            omg.z * e0.z * einv.z / (s3v.z + kEps), omg.w * e0.w * einv.w / (s3v.w + kEps));
    float4 w5 = make_float4(omg.x * e1.x * einv.x / (s5v.x + kEps), omg.y * e1.y * einv.y / (s5v.y + kEps),
                            omg.z * e1.z * einv.z / (s5v.z + kEps), omg.w * e1.w * einv.w / (s5v.w + kEps));
    float4 w7 = make_float4(omg.x * e2.x * einv.x / (s7v.x + kEps), omg.y * e2.y * einv.y / (s7v.y + kEps),
                            omg.z * e2.z * einv.z / (s7v.z + kEps), omg.w * e2.w * einv.w / (s7v.w + kEps));

    // Q = (w3*c3 + w5*c5 + w7*c7)*D0 + g*DL   (center Dt coef cancels)
    float4 d0 = ld4(D0 + p);
    float4 dl = ld4(DL + p);
    float4 cw = f4fma(w3, a3r[4], f4fma(w5, c5v, f4mul(w7, c7v)));
    float4 Qv = f4fma(cw, d0, f4mul(g, dl));
    *(float4*)(&g_Q[p]) = Qv;

    // ---- Merge (a7 from LDS, a5 from global L2/L3, a3 from regs)
    //      + store fp16 Wh + fused step 1 (fp32 wv) ----
    float acc[4] = {Qv.x, Qv.y, Qv.z, Qv.w};
    int oi = 0;
#pragma unroll
    for (int dy = -3; dy <= 3; ++dy) {
        int ny = y + dy;
        bool rv = (ny >= 0) && (ny < kH);
        float rowv[12];   // D0 row window, x0-4 .. x0+7
        if (rv) {
            const float* dr = d0b + ny * kW;
#pragma unroll
            for (int s = 0; s < 3; ++s) {
                int xb = x0 + (s - 1) * 4;
                float4 v = (xb >= 0 && xb + 3 < kW) ? ld4(dr + xb) : zero;
                rowv[s * 4 + 0] = v.x; rowv[s * 4 + 1] = v.y;
                rowv[s * 4 + 2] = v.z; rowv[s * 4 + 3] = v.w;
            }
        } else {
#pragma unroll
            for (int s = 0; s < 12; ++s) rowv[s] = 0.f;
        }
#pragma unroll
        for (int dx = -3; dx <= 3; ++dx) {
            if (dy == 0 && dx == 0) continue;
            int i = (dy + 3) * 7 + (dx + 3);
            float4 wv = f4mul(w7, tof4(*(const half4*)(&sh7[i * (kBlockP * 4) + sb])));
            if (dy >= -2 && dy <= 2 && dx >= -2 && dx <= 2)
                wv = f4fma(w5, ld4(a5p + (size_t)((dy + 2) * 5 + (dx + 2)) * kHW), wv);
            if (dy >= -1 && dy <= 1 && dx >= -1 && dx <= 1)
                wv = f4fma(w3, a3r[(dy + 1) * 3 + (dx + 1)], wv);
            *(half4*)(&g_Wh[(size_t)oi * kN + p]) = toh4(wv);
            acc[0] = fmaf(wv.x, rowv[4 + 0 + dx], acc[0]);
            acc[1] = fmaf(wv.y, rowv[4 + 1 + dx], acc[1]);
            acc[2] = fmaf(wv.z, rowv[4 + 2 + dx], acc[2]);
            acc[3] = fmaf(wv.w, rowv[4 + 3 + dx], acc[3]);
            ++oi;
        }
    }
    float4 o;
    o.x = fminf(fmaxf(acc[0], 0.f), kDmax);
    o.y = fminf(fmaxf(acc[1], 0.f), kDmax);
    o.z = fminf(fmaxf(acc[2], 0.f), kDmax);
    o.w = fminf(fmaxf(acc[3], 0.f), kDmax);
    *(float4*)(&g_ping[p]) = o;               // D1
}

// One propagation step, 8 pixels/thread, balanced 512-block grid (frozen).
__global__ __launch_bounds__(kBlock) void step_kernel(
    const float* __restrict__ Din_ext, float* __restrict__ Dout_ext,
    int src_g, int dst_g)
{
    if (threadIdx.x >= kUnitsPerBlk) return;
    const float* Din = src_g ? g_ping : Din_ext;
    float* Dout = dst_g ? g_ping : Dout_ext;

    int t = blockIdx.x * kUnitsPerBlk + threadIdx.x;   // 0 .. kN/8-1
    int p = t * 8;
    int b = p / kHW;                             // kHW % 8 == 0
    int rem = p - b * kHW;
    int y = rem / kW;                            // kW % 8 == 0: stays in one row
    int x0 = rem - y * kW;
    const float* dinb = Din + (size_t)b * kHW;

    float acc[8];
    {
        float4 q0 = ld4(&g_Q[p]);
        float4 q1 = ld4(&g_Q[p + 4]);
        acc[0] = q0.x; acc[1] = q0.y; acc[2] = q0.z; acc[3] = q0.w;
        acc[4] = q1.x; acc[5] = q1.y; acc[6] = q1.z; acc[7] = q1.w;
    }

    int oi = 0;
#pragma unroll
    for (int dy = -3; dy <= 3; ++dy) {
        int ny = y + dy;
        bool rv = (ny >= 0) && (ny < kH);
        if (!rv) { oi += (dy == 0) ? 6 : 7; continue; }   // zero contribution
        const float* dr = dinb + ny * kW;

        float rowv[16];   // covers x0-4 .. x0+11
#pragma unroll
        for (int s = 0; s < 4; ++s) {
            int xb = x0 + (s - 1) * 4;
            float4 v = (xb >= 0 && xb + 3 < kW) ? ld4(dr + xb)
                                                : make_float4(0.f, 0.f, 0.f, 0.f);
            rowv[s * 4 + 0] = v.x; rowv[s * 4 + 1] = v.y;
            rowv[s * 4 + 2] = v.z; rowv[s * 4 + 3] = v.w;
        }
#pragma unroll
        for (int dx = -3; dx <= 3; ++dx) {
            if (dy == 0 && dx == 0) continue;
            half8 w = *(const half8*)(&g_Wh[(size_t)oi * kN + p]);
#pragma unroll
            for (int j = 0; j < 8; ++j)
                acc[j] = fmaf((float)w[j], rowv[4 + j + dx], acc[j]);
            ++oi;
        }
    }

#pragma unroll
    for (int j = 0; j < 8; ++j)
        acc[j] = fminf(fmaxf(acc[j], 0.f), kDmax);
    *(float4*)(&Dout[p])     = make_float4(acc[0], acc[1], acc[2], acc[3]);
    *(float4*)(&Dout[p + 4]) = make_float4(acc[4], acc[5], acc[6], acc[7]);
}

extern "C" void kernel_launch(void* const* d_in, const int* in_sizes, int n_in,
                              void* d_out, int out_size, void* d_ws, size_t ws_size,
                              hipStream_t stream) {
    const float* D0 = (const float*)d_in[0];
    const float* DL = (const float*)d_in[1];
    const float* ML = (const float*)d_in[2];
    const float* A3 = (const float*)d_in[3];
    const float* A5 = (const float*)d_in[4];
    const float* A7 = (const float*)d_in[5];
    const float* SG = (const float*)d_in[6];
    const float* AL = (const float*)d_in[7];
    float* out = (float*)d_out;

    dim3 gridP(kN / 4 / kBlockP);   // 1672, exact (prep: 4 px/thread, 128-thr blocks)
    dim3 gridS(kStepGrid);          // 512 = exactly 2 blocks/CU

    // prep computes Wh, Q AND D1 (fused step 1) -> g_ping
    prep_kernel<<<gridP, dim3(kBlockP), 0, stream>>>(D0, DL, ML, A3, A5, A7, SG, AL);

    // 5 remaining steps: ping -> out -> ping -> out -> ping -> out
    step_kernel<<<gridS, dim3(kBlock), 0, stream>>>(nullptr, out, 1, 0);
    step_kernel<<<gridS, dim3(kBlock), 0, stream>>>(out, nullptr, 0, 1);
    step_kernel<<<gridS, dim3(kBlock), 0, stream>>>(nullptr, out, 1, 0);
    step_kernel<<<gridS, dim3(kBlock), 0, stream>>>(out, nullptr, 0, 1);
    step_kernel<<<gridS, dim3(kBlock), 0, stream>>>(nullptr, out, 1, 0);
}

// Round 17
// 189.366 us; speedup vs baseline: 1.0344x; 1.0344x over previous
//
#include <hip/hip_runtime.h>

namespace {
constexpr int kB = 2;
constexpr int kH = 352;
constexpr int kW = 1216;
constexpr int kHW = kH * kW;        // 428032
constexpr int kN = kB * kHW;        // 856064
constexpr float kDmax = 80.0f;
constexpr float kEps = 1e-6f;
constexpr int kBlock = 256;         // step kernels
constexpr int kBlockP = 128;        // prep blocks
constexpr int kStepGrid = 512;      // exactly 2 blocks/CU
constexpr int kUnitsPerBlk = 209;   // 512*209 = kN/8 exactly -> perfect balance
}

typedef _Float16 half_t;
typedef __attribute__((ext_vector_type(4))) _Float16 half4;
typedef __attribute__((ext_vector_type(8))) _Float16 half8;

// Module-owned workspace, fully rewritten from inputs on every launch.
__device__ half_t g_Wh[(size_t)48 * kN];  // merged weights, fp16, ch-major (~82 MB)
__device__ float  g_Q[kN];                // fp32 constant term
__device__ float  g_ping[kN];             // Dt ping buffer

__device__ __forceinline__ float4 ld4(const float* p) { return *(const float4*)p; }
__device__ __forceinline__ float4 f4add(float4 a, float4 b) {
    return make_float4(a.x + b.x, a.y + b.y, a.z + b.z, a.w + b.w);
}
__device__ __forceinline__ float4 f4mul(float4 a, float4 b) {
    return make_float4(a.x * b.x, a.y * b.y, a.z * b.z, a.w * b.w);
}
__device__ __forceinline__ float4 f4fma(float4 a, float4 b, float4 c) {
    return make_float4(fmaf(a.x, b.x, c.x), fmaf(a.y, b.y, c.y),
                       fmaf(a.z, b.z, c.z), fmaf(a.w, b.w, c.w));
}
__device__ __forceinline__ float4 f4abs(float4 a) {
    return make_float4(fabsf(a.x), fabsf(a.y), fabsf(a.z), fabsf(a.w));
}
__device__ __forceinline__ float4 f4max(float4 a, float4 b) {
    return make_float4(fmaxf(a.x, b.x), fmaxf(a.y, b.y),
                       fmaxf(a.z, b.z), fmaxf(a.w, b.w));
}
__device__ __forceinline__ half4 toh4(float4 v) {
    half4 h;
    h[0] = (half_t)v.x; h[1] = (half_t)v.y; h[2] = (half_t)v.z; h[3] = (half_t)v.w;
    return h;
}
__device__ __forceinline__ float4 tof4(half4 h) {
    return make_float4((float)h[0], (float)h[1], (float)h[2], (float)h[3]);
}

// Single-pass merged-weight precompute + fused first step — R15 configuration
// (best measured: prep 138.8 us, total 189.5) restored verbatim, with a5
// stash back in LDS (R16's a5-from-global cost +47 MB FETCH, +2.5 us).
// Added this round: T5 s_setprio(1) around the merge/store phase. Prep waves
// drift barrier-free (attn-like phase diversity, m191 +4-7%), unlike the
// lockstep-GEMM null (m190). Zero-risk experiment.
__global__ __launch_bounds__(kBlockP) void prep_kernel(
    const float* __restrict__ D0, const float* __restrict__ DL,
    const float* __restrict__ ML, const float* __restrict__ A3,
    const float* __restrict__ A5, const float* __restrict__ A7,
    const float* __restrict__ SG, const float* __restrict__ AL)
{
    __shared__ half_t sh7[49 * kBlockP * 4];   // 50176 B
    __shared__ half_t sh5[25 * kBlockP * 4];   // 25600 B  (total 74 KiB -> 2 blocks/CU)

    int tid = threadIdx.x;
    int t = blockIdx.x * kBlockP + tid;       // 0 .. kN/4-1
    int p = t * 4;
    int b = p / kHW;                          // kHW % 512 == 0: block batch-uniform
    int rem = p - b * kHW;
    int y = rem / kW;                         // kW % 4 == 0: 4-px group stays in row
    int x0 = rem - y * kW;
    int sb = tid * 4;                         // this thread's LDS pixel base

    const float* a3p = A3 + (size_t)b * 9 * kHW + rem;
    const float* a5p = A5 + (size_t)b * 25 * kHW + rem;
    const float* a7p = A7 + (size_t)b * 49 * kHW + rem;
    const float* sgp = SG + (size_t)b * 3 * kHW + rem;
    const float* d0b = D0 + (size_t)b * kHW;

    float4 zero = make_float4(0.f, 0.f, 0.f, 0.f);

    // ---- Stream a7: 6x8 batches + 1; abs-sum, stash fp16 ----
    float4 s7v = zero, c7v = zero;
#pragma unroll
    for (int ch = 0; ch < 6; ++ch) {
        float4 buf[8];
#pragma unroll
        for (int j = 0; j < 8; ++j) buf[j] = ld4(a7p + (size_t)(ch * 8 + j) * kHW);
#pragma unroll
        for (int j = 0; j < 8; ++j) {
            int c = ch * 8 + j;
            if (c == 24) c7v = buf[j];
            s7v = f4add(s7v, f4abs(buf[j]));
            *(half4*)(&sh7[c * (kBlockP * 4) + sb]) = toh4(buf[j]);
        }
    }
    {
        float4 l = ld4(a7p + (size_t)48 * kHW);
        s7v = f4add(s7v, f4abs(l));
        *(half4*)(&sh7[48 * (kBlockP * 4) + sb]) = toh4(l);
    }

    // ---- Stream a5: 3x8 batches + 1; abs-sum, stash fp16 ----
    float4 s5v = zero, c5v = zero;
#pragma unroll
    for (int ch = 0; ch < 3; ++ch) {
        float4 buf[8];
#pragma unroll
        for (int j = 0; j < 8; ++j) buf[j] = ld4(a5p + (size_t)(ch * 8 + j) * kHW);
#pragma unroll
        for (int j = 0; j < 8; ++j) {
            int c = ch * 8 + j;
            if (c == 12) c5v = buf[j];
            s5v = f4add(s5v, f4abs(buf[j]));
            *(half4*)(&sh5[c * (kBlockP * 4) + sb]) = toh4(buf[j]);
        }
    }
    {
        float4 l = ld4(a5p + (size_t)24 * kHW);
        s5v = f4add(s5v, f4abs(l));
        *(half4*)(&sh5[24 * (kBlockP * 4) + sb]) = toh4(l);
    }

    // ---- a3 stays in registers (9 float4 = 36 VGPR) ----
    float4 a3r[9];
    float4 s3v = zero;
#pragma unroll
    for (int c = 0; c < 9; ++c) a3r[c] = ld4(a3p + (size_t)c * kHW);
#pragma unroll
    for (int c = 0; c < 9; ++c) s3v = f4add(s3v, f4abs(a3r[c]));

    // ---- Per-pixel scalars ----
    float4 g0 = ld4(sgp);
    float4 g1 = ld4(sgp + kHW);
    float4 g2 = ld4(sgp + 2 * kHW);
    float4 mx = f4max(g0, f4max(g1, g2));
    float4 e0 = make_float4(expf(g0.x - mx.x), expf(g0.y - mx.y), expf(g0.z - mx.z), expf(g0.w - mx.w));
    float4 e1 = make_float4(expf(g1.x - mx.x), expf(g1.y - mx.y), expf(g1.z - mx.z), expf(g1.w - mx.w));
    float4 e2 = make_float4(expf(g2.x - mx.x), expf(g2.y - mx.y), expf(g2.z - mx.z), expf(g2.w - mx.w));
    float4 einv = make_float4(1.f / (e0.x + e1.x + e2.x), 1.f / (e0.y + e1.y + e2.y),
                              1.f / (e0.z + e1.z + e2.z), 1.f / (e0.w + e1.w + e2.w));

    float4 alv = ld4(AL + p);
    float4 ml  = ld4(ML + p);
    float4 al = make_float4(fminf(fmaxf(alv.x, 0.f), 1.f), fminf(fmaxf(alv.y, 0.f), 1.f),
                            fminf(fmaxf(alv.z, 0.f), 1.f), fminf(fmaxf(alv.w, 0.f), 1.f));
    float4 mk = make_float4(ml.x > 0.5f ? 1.f : 0.f, ml.y > 0.5f ? 1.f : 0.f,
                            ml.z > 0.5f ? 1.f : 0.f, ml.w > 0.5f ? 1.f : 0.f);
    float4 g = f4mul(al, mk);
    float4 omg = make_float4(1.f - g.x, 1.f - g.y, 1.f - g.z, 1.f - g.w);

    float4 w3 = make_float4(omg.x * e0.x * einv.x / (s3v.x + kEps), omg.y * e0.y * einv.y / (s3v.y + kEps),
                            omg.z * e0.z * einv.z / (s3v.z + kEps), omg.w * e0.w * einv.w / (s3v.w + kEps));
    float4 w5 = make_float4(omg.x * e1.x * einv.x / (s5v.x + kEps), omg.y * e1.y * einv.y / (s5v.y + kEps),
                            omg.z * e1.z * einv.z / (s5v.z + kEps), omg.w * e1.w * einv.w / (s5v.w + kEps));
    float4 w7 = make_float4(omg.x * e2.x * einv.x / (s7v.x + kEps), omg.y * e2.y * einv.y / (s7v.y + kEps),
                            omg.z * e2.z * einv.z / (s7v.z + kEps), omg.w * e2.w * einv.w / (s7v.w + kEps));

    // Q = (w3*c3 + w5*c5 + w7*c7)*D0 + g*DL   (center Dt coef cancels)
    float4 d0 = ld4(D0 + p);
    float4 dl = ld4(DL + p);
    float4 cw = f4fma(w3, a3r[4], f4fma(w5, c5v, f4mul(w7, c7v)));
    float4 Qv = f4fma(cw, d0, f4mul(g, dl));
    *(float4*)(&g_Q[p]) = Qv;

    // ---- Merge from LDS + store fp16 Wh + fused step 1 (fp32 wv) ----
    __builtin_amdgcn_s_setprio(1);            // T5: favor this wave's VALU/store
    float acc[4] = {Qv.x, Qv.y, Qv.z, Qv.w};
    int oi = 0;
#pragma unroll
    for (int dy = -3; dy <= 3; ++dy) {
        int ny = y + dy;
        bool rv = (ny >= 0) && (ny < kH);
        float rowv[12];   // D0 row window, x0-4 .. x0+7
        if (rv) {
            const float* dr = d0b + ny * kW;
#pragma unroll
            for (int s = 0; s < 3; ++s) {
                int xb = x0 + (s - 1) * 4;
                float4 v = (xb >= 0 && xb + 3 < kW) ? ld4(dr + xb) : zero;
                rowv[s * 4 + 0] = v.x; rowv[s * 4 + 1] = v.y;
                rowv[s * 4 + 2] = v.z; rowv[s * 4 + 3] = v.w;
            }
        } else {
#pragma unroll
            for (int s = 0; s < 12; ++s) rowv[s] = 0.f;
        }
#pragma unroll
        for (int dx = -3; dx <= 3; ++dx) {
            if (dy == 0 && dx == 0) continue;
            int i = (dy + 3) * 7 + (dx + 3);
            float4 wv = f4mul(w7, tof4(*(const half4*)(&sh7[i * (kBlockP * 4) + sb])));
            if (dy >= -2 && dy <= 2 && dx >= -2 && dx <= 2)
                wv = f4fma(w5, tof4(*(const half4*)(&sh5[((dy + 2) * 5 + (dx + 2)) * (kBlockP * 4) + sb])), wv);
            if (dy >= -1 && dy <= 1 && dx >= -1 && dx <= 1)
                wv = f4fma(w3, a3r[(dy + 1) * 3 + (dx + 1)], wv);
            *(half4*)(&g_Wh[(size_t)oi * kN + p]) = toh4(wv);
            acc[0] = fmaf(wv.x, rowv[4 + 0 + dx], acc[0]);
            acc[1] = fmaf(wv.y, rowv[4 + 1 + dx], acc[1]);
            acc[2] = fmaf(wv.z, rowv[4 + 2 + dx], acc[2]);
            acc[3] = fmaf(wv.w, rowv[4 + 3 + dx], acc[3]);
            ++oi;
        }
    }
    __builtin_amdgcn_s_setprio(0);
    float4 o;
    o.x = fminf(fmaxf(acc[0], 0.f), kDmax);
    o.y = fminf(fmaxf(acc[1], 0.f), kDmax);
    o.z = fminf(fmaxf(acc[2], 0.f), kDmax);
    o.w = fminf(fmaxf(acc[3], 0.f), kDmax);
    *(float4*)(&g_ping[p]) = o;               // D1
}

// One propagation step, 8 pixels/thread, balanced 512-block grid (frozen:
// ~10.2 us each, at the observed L3 demand ceiling ~9 TB/s).
__global__ __launch_bounds__(kBlock) void step_kernel(
    const float* __restrict__ Din_ext, float* __restrict__ Dout_ext,
    int src_g, int dst_g)
{
    if (threadIdx.x >= kUnitsPerBlk) return;
    const float* Din = src_g ? g_ping : Din_ext;
    float* Dout = dst_g ? g_ping : Dout_ext;

    int t = blockIdx.x * kUnitsPerBlk + threadIdx.x;   // 0 .. kN/8-1
    int p = t * 8;
    int b = p / kHW;                             // kHW % 8 == 0
    int rem = p - b * kHW;
    int y = rem / kW;                            // kW % 8 == 0: stays in one row
    int x0 = rem - y * kW;
    const float* dinb = Din + (size_t)b * kHW;

    float acc[8];
    {
        float4 q0 = ld4(&g_Q[p]);
        float4 q1 = ld4(&g_Q[p + 4]);
        acc[0] = q0.x; acc[1] = q0.y; acc[2] = q0.z; acc[3] = q0.w;
        acc[4] = q1.x; acc[5] = q1.y; acc[6] = q1.z; acc[7] = q1.w;
    }

    int oi = 0;
#pragma unroll
    for (int dy = -3; dy <= 3; ++dy) {
        int ny = y + dy;
        bool rv = (ny >= 0) && (ny < kH);
        if (!rv) { oi += (dy == 0) ? 6 : 7; continue; }   // zero contribution
        const float* dr = dinb + ny * kW;

        float rowv[16];   // covers x0-4 .. x0+11
#pragma unroll
        for (int s = 0; s < 4; ++s) {
            int xb = x0 + (s - 1) * 4;
            float4 v = (xb >= 0 && xb + 3 < kW) ? ld4(dr + xb)
                                                : make_float4(0.f, 0.f, 0.f, 0.f);
            rowv[s * 4 + 0] = v.x; rowv[s * 4 + 1] = v.y;
            rowv[s * 4 + 2] = v.z; rowv[s * 4 + 3] = v.w;
        }
#pragma unroll
        for (int dx = -3; dx <= 3; ++dx) {
            if (dy == 0 && dx == 0) continue;
            half8 w = *(const half8*)(&g_Wh[(size_t)oi * kN + p]);
#pragma unroll
            for (int j = 0; j < 8; ++j)
                acc[j] = fmaf((float)w[j], rowv[4 + j + dx], acc[j]);
            ++oi;
        }
    }

#pragma unroll
    for (int j = 0; j < 8; ++j)
        acc[j] = fminf(fmaxf(acc[j], 0.f), kDmax);
    *(float4*)(&Dout[p])     = make_float4(acc[0], acc[1], acc[2], acc[3]);
    *(float4*)(&Dout[p + 4]) = make_float4(acc[4], acc[5], acc[6], acc[7]);
}

extern "C" void kernel_launch(void* const* d_in, const int* in_sizes, int n_in,
                              void* d_out, int out_size, void* d_ws, size_t ws_size,
                              hipStream_t stream) {
    const float* D0 = (const float*)d_in[0];
    const float* DL = (const float*)d_in[1];
    const float* ML = (const float*)d_in[2];
    const float* A3 = (const float*)d_in[3];
    const float* A5 = (const float*)d_in[4];
    const float* A7 = (const float*)d_in[5];
    const float* SG = (const float*)d_in[6];
    const float* AL = (const float*)d_in[7];
    float* out = (float*)d_out;

    dim3 gridP(kN / 4 / kBlockP);   // 1672, exact (prep: 4 px/thread, 128-thr blocks)
    dim3 gridS(kStepGrid);          // 512 = exactly 2 blocks/CU

    // prep computes Wh, Q AND D1 (fused step 1) -> g_ping
    prep_kernel<<<gridP, dim3(kBlockP), 0, stream>>>(D0, DL, ML, A3, A5, A7, SG, AL);

    // 5 remaining steps: ping -> out -> ping -> out -> ping -> out
    step_kernel<<<gridS, dim3(kBlock), 0, stream>>>(nullptr, out, 1, 0);
    step_kernel<<<gridS, dim3(kBlock), 0, stream>>>(out, nullptr, 0, 1);
    step_kernel<<<gridS, dim3(kBlock), 0, stream>>>(nullptr, out, 1, 0);
    step_kernel<<<gridS, dim3(kBlock), 0, stream>>>(out, nullptr, 0, 1);
    step_kernel<<<gridS, dim3(kBlock), 0, stream>>>(nullptr, out, 1, 0);
}